// Round 4
// baseline (25.997 us; speedup 1.0000x reference)
//
#include <hip/hip_runtime.h>
#include <cmath>

#define NMAX   8
#define NM     25      // (LMAX+1)^2
#define NSPEC  3
#define NPAIR  6
#define NTRIU  36
#define NATOM  512
#define NSLOTP 76      // padded column stride for transposed slabs (12 mod 32 -> bank-spread)
#define NOUT   1080    // NPAIR * 5 * NTRIU
#define NQUAD  270     // NOUT / 4

struct Params {
    float W[NMAX * NMAX];   // W_ORTHO (symmetric)
    float invnorm[NMAX];    // 1 / norm_factor[alpha]
    float ycoef[NM];        // sph-harm coefficients * 4*pi
    float lscale[5];        // pi*sqrt(8/(2l+1))
    float pairf[NPAIR];     // sqrt(2) for unlike species pairs
};

__device__ const int TRIU_N[NTRIU] = {0,0,0,0,0,0,0,0, 1,1,1,1,1,1,1, 2,2,2,2,2,2,
                                      3,3,3,3,3, 4,4,4,4, 5,5,5, 6,6, 7};
__device__ const int TRIU_P[NTRIU] = {0,1,2,3,4,5,6,7, 1,2,3,4,5,6,7, 2,3,4,5,6,7,
                                      3,4,5,6,7, 4,5,6,7, 5,6,7, 6,7, 7};
__device__ const int PAIR_S1[NPAIR] = {0,0,0,1,1,2};
__device__ const int PAIR_S2[NPAIR] = {0,1,2,1,2,2};
__device__ const int L_OF_M[NM] = {0, 1,1,1, 2,2,2,2,2, 3,3,3,3,3,3,3, 4,4,4,4,4,4,4,4,4};

// per-neighbor heavy compute: writes g (8) and Y (25) into transposed slabs at column `col`
__device__ __forceinline__ int neighbor_compute(
    const float* __restrict__ pos, const int* __restrict__ Z, const Params& prm,
    float xi, float yi, float zi, int ja, int col,
    float* __restrict__ g_t, float* __restrict__ y_t) {
    const float dx = xi - pos[ja * 3 + 0];
    const float dy = yi - pos[ja * 3 + 1];
    const float dz = zi - pos[ja * 3 + 2];
    const float d2 = dx * dx + dy * dy + dz * dz;
    const float dist = sqrtf(d2);
    const float inv  = dist > 0.f ? 1.f / dist : 0.f;
    const float x = dx * inv, y = dy * inv, z = dz * inv;
    const float x2 = x * x, y2 = y * y, z2 = z * z;
    const float r2 = x2 + y2 + z2;

    float Yv[NM];
    Yv[0]  = prm.ycoef[0];
    Yv[1]  = prm.ycoef[1]  * y;
    Yv[2]  = prm.ycoef[2]  * z;
    Yv[3]  = prm.ycoef[3]  * x;
    Yv[4]  = prm.ycoef[4]  * x * y;
    Yv[5]  = prm.ycoef[5]  * y * z;
    Yv[6]  = prm.ycoef[6]  * (3.f * z2 - r2);
    Yv[7]  = prm.ycoef[7]  * x * z;
    Yv[8]  = prm.ycoef[8]  * (x2 - y2);
    Yv[9]  = prm.ycoef[9]  * y * (3.f * x2 - y2);
    Yv[10] = prm.ycoef[10] * x * y * z;
    Yv[11] = prm.ycoef[11] * y * (5.f * z2 - r2);
    Yv[12] = prm.ycoef[12] * z * (5.f * z2 - 3.f * r2);
    Yv[13] = prm.ycoef[13] * x * (5.f * z2 - r2);
    Yv[14] = prm.ycoef[14] * z * (x2 - y2);
    Yv[15] = prm.ycoef[15] * x * (x2 - 3.f * y2);
    Yv[16] = prm.ycoef[16] * x * y * (x2 - y2);
    Yv[17] = prm.ycoef[17] * y * z * (3.f * x2 - y2);
    Yv[18] = prm.ycoef[18] * x * y * (7.f * z2 - r2);
    Yv[19] = prm.ycoef[19] * y * z * (7.f * z2 - 3.f * r2);
    Yv[20] = prm.ycoef[20] * (35.f * z2 * z2 - 30.f * z2 * r2 + 3.f * r2 * r2);
    Yv[21] = prm.ycoef[21] * x * z * (7.f * z2 - 3.f * r2);
    Yv[22] = prm.ycoef[22] * (x2 - y2) * (7.f * z2 - r2);
    Yv[23] = prm.ycoef[23] * x * z * (x2 - 3.f * y2);
    Yv[24] = prm.ycoef[24] * (x2 * x2 - 6.f * x2 * y2 + y2 * y2);
#pragma unroll
    for (int m = 0; m < NM; ++m) y_t[m * NSLOTP + col] = Yv[m];

    const float dr = 5.f - dist;
    float bas[NMAX];
    float drp = dr * dr * dr;
#pragma unroll
    for (int a = 0; a < NMAX; ++a) { bas[a] = drp * prm.invnorm[a]; drp *= dr; }
#pragma unroll
    for (int n = 0; n < NMAX; ++n) {
        float acc = 0.f;
#pragma unroll
        for (int a = 0; a < NMAX; ++a) acc += bas[a] * prm.W[n * NMAX + a];
        g_t[n * NSLOTP + col] = acc;
    }
    const int zz = Z[ja];
    return (zz == 1) ? 0 : (zz == 6) ? 1 : 2;
}

__global__ __launch_bounds__(256)
void soap_kernel(const float* __restrict__ pos, const int* __restrict__ Z,
                 float* __restrict__ out, Params prm) {
    __shared__ int   idx_lds[NATOM];
    __shared__ float g_t[NMAX * NSLOTP];
    __shared__ float y_t[NM * NSLOTP];
    __shared__ float c_lds[NSPEC * NMAX * 5 * 12];   // l-blocked, zero-padded to 12
    __shared__ int   s_lds[64];
    __shared__ int   wcnt[8], wbase[8], scal[4];

    const int tid  = threadIdx.x;
    const int lane = tid & 63;
    const int w    = tid >> 6;
    const int site = blockIdx.x;        // b*NATOM + i
    const int b    = site >> 9;

    const float xi = pos[site * 3 + 0];
    const float yi = pos[site * 3 + 1];
    const float zi = pos[site * 3 + 2];

    // zero-init slabs (padding columns must read as 0) and c
    for (int i = tid; i < NMAX * NSLOTP; i += 256) g_t[i] = 0.f;
    for (int i = tid; i < NM * NSLOTP;  i += 256) y_t[i] = 0.f;
    for (int i = tid; i < NSPEC * NMAX * 60; i += 256) c_lds[i] = 0.f;

    // ---- Phase A1: cutoff test (both 256-chunks), ballot-scan compaction ----
    const int ja0 = (b << 9) + tid;
    const int ja1 = ja0 + 256;
    float dx, dy, dz;
    dx = xi - pos[ja0 * 3 + 0]; dy = yi - pos[ja0 * 3 + 1]; dz = zi - pos[ja0 * 3 + 2];
    const float d2a = dx * dx + dy * dy + dz * dz;
    dx = xi - pos[ja1 * 3 + 0]; dy = yi - pos[ja1 * 3 + 1]; dz = zi - pos[ja1 * 3 + 2];
    const float d2b = dx * dx + dy * dy + dz * dz;
    const bool p0 = d2a < 25.0f, p1 = d2b < 25.0f;
    const unsigned long long m0 = __ballot(p0), m1 = __ballot(p1);
    if (lane == 0) { wcnt[w] = __popcll(m0); wcnt[4 + w] = __popcll(m1); }
    __syncthreads();
    if (tid == 0) {
        int run = 0;
        for (int k = 0; k < 8; ++k) { wbase[k] = run; run += wcnt[k]; }
        scal[0] = run;
    }
    __syncthreads();
    const unsigned long long ltm = (1ull << lane) - 1ull;
    if (p0) idx_lds[wbase[w]     + __popcll(m0 & ltm)] = ja0;
    if (p1) idx_lds[wbase[4 + w] + __popcll(m1 & ltm)] = ja1;
    __syncthreads();
    const int M = scal[0];

    const int  own_n = tid & 7;
    const int  own_m = tid >> 3;
    const bool owner = (tid < NMAX * NM);   // 200 threads
    float c0 = 0.f, c1 = 0.f, c2 = 0.f;

    const bool fast = (M <= 64);
    if (fast) {
        // ---- single-wave species bucketing (deterministic, 4-aligned buckets) ----
        if (w == 0) {
            const int myidx = (lane < M) ? idx_lds[lane] : -1;
            int sp = -1;
            if (myidx >= 0) { const int zz = Z[myidx]; sp = (zz == 1) ? 0 : (zz == 6) ? 1 : 2; }
            const unsigned long long b0 = __ballot(sp == 0);
            const unsigned long long b1 = __ballot(sp == 1);
            const unsigned long long b2 = __ballot(sp == 2);
            const int n0 = __popcll(b0), n1 = __popcll(b1);
            const int r1 = (n0 + 3) & ~3;
            const int r2 = r1 + ((n1 + 3) & ~3);
            const int mp = r2 + __popcll(b2);
            int ppos = -1;
            if (sp == 0)      ppos = __popcll(b0 & ltm);
            else if (sp == 1) ppos = r1 + __popcll(b1 & ltm);
            else if (sp == 2) ppos = r2 + __popcll(b2 & ltm);
            idx_lds[lane] = -1;                 // after myidx read (per-wave DS in-order)
            if (lane < 8) idx_lds[64 + lane] = -1;
            if (ppos >= 0) idx_lds[ppos] = myidx;
            if (lane == 0) { scal[1] = r1; scal[2] = r2; scal[3] = mp; }
        }
        __syncthreads();
        const int R1 = scal[1], R2 = scal[2], Mp = scal[3];

        // ---- Phase A2: one thread per bucketed slot ----
        if (tid < Mp) {
            const int ja = idx_lds[tid];
            if (ja >= 0)
                neighbor_compute(pos, Z, prm, xi, yi, zi, ja, tid, g_t, y_t);
        }
        __syncthreads();

        // ---- Phase B: per-species contiguous ranges, float4 LDS reads ----
        if (owner) {
            const float4* gp = (const float4*)&g_t[own_n * NSLOTP];
            const float4* yp = (const float4*)&y_t[own_m * NSLOTP];
            const int q1 = R1 >> 2, q2 = R2 >> 2, q3 = (Mp + 3) >> 2;
            for (int q = 0; q < q1; ++q) {
                const float4 g4 = gp[q], y4 = yp[q];
                c0 += g4.x * y4.x + g4.y * y4.y + g4.z * y4.z + g4.w * y4.w;
            }
            for (int q = q1; q < q2; ++q) {
                const float4 g4 = gp[q], y4 = yp[q];
                c1 += g4.x * y4.x + g4.y * y4.y + g4.z * y4.z + g4.w * y4.w;
            }
            for (int q = q2; q < q3; ++q) {
                const float4 g4 = gp[q], y4 = yp[q];
                c2 += g4.x * y4.x + g4.y * y4.y + g4.z * y4.z + g4.w * y4.w;
            }
        }
    } else {
        // ---- fallback (M > 64, astronomically rare): slab loop with select ----
        for (int rb = 0; rb < M; rb += 64) {
            const int cnt = min(64, M - rb);
            if (tid < cnt) {
                const int ja = idx_lds[rb + tid];
                s_lds[tid] = neighbor_compute(pos, Z, prm, xi, yi, zi, ja, tid, g_t, y_t);
            }
            __syncthreads();
            if (owner) {
                for (int sl = 0; sl < cnt; ++sl) {
                    const float g  = g_t[own_n * NSLOTP + sl];
                    const float yv = y_t[own_m * NSLOTP + sl];
                    const int   ss = s_lds[sl];
                    const float prod = g * yv;
                    c0 += (ss == 0) ? prod : 0.f;
                    c1 += (ss == 1) ? prod : 0.f;
                    c2 += (ss == 2) ? prod : 0.f;
                }
            }
            __syncthreads();
        }
    }

    if (owner) {
        const int l = L_OF_M[own_m];
        const int k = own_m - l * l;
        c_lds[((0 * NMAX + own_n) * 5 + l) * 12 + k] = c0;
        c_lds[((1 * NMAX + own_n) * 5 + l) * 12 + k] = c1;
        c_lds[((2 * NMAX + own_n) * 5 + l) * 12 + k] = c2;
    }
    __syncthreads();

    // ---- Phase C: power spectrum, 4 outputs per task, uniform 12-term dot ----
    for (int t4 = tid; t4 < NQUAD; t4 += 256) {
        const int o0  = t4 << 2;
        const int q   = o0 / 180;
        const int rem = o0 - q * 180;
        const int l   = rem / 36;
        const int t0  = rem - l * 36;
        const int s1 = PAIR_S1[q], s2 = PAIR_S2[q];
        const float sc = prm.pairf[q] * prm.lscale[l];
        float res[4];
#pragma unroll
        for (int j = 0; j < 4; ++j) {
            const int t = t0 + j;
            const int n = TRIU_N[t], p = TRIU_P[t];
            const float4* ra = (const float4*)&c_lds[((s1 * NMAX + n) * 5 + l) * 12];
            const float4* rb = (const float4*)&c_lds[((s2 * NMAX + p) * 5 + l) * 12];
            const float4 a0 = ra[0], b0 = rb[0];
            const float4 a1 = ra[1], b1 = rb[1];
            const float4 a2 = ra[2], b2 = rb[2];
            float sum = a0.x * b0.x + a0.y * b0.y + a0.z * b0.z + a0.w * b0.w
                      + a1.x * b1.x + a1.y * b1.y + a1.z * b1.z + a1.w * b1.w
                      + a2.x * b2.x + a2.y * b2.y + a2.z * b2.z + a2.w * b2.w;
            res[j] = sum * ((n != p) ? sc * 1.41421356237309515f : sc);
        }
        *(float4*)&out[site * NOUT + o0] = make_float4(res[0], res[1], res[2], res[3]);
    }
}

extern "C" void kernel_launch(void* const* d_in, const int* in_sizes, int n_in,
                              void* d_out, int out_size, void* d_ws, size_t ws_size,
                              hipStream_t stream) {
    const float* pos = (const float*)d_in[0];
    const int*   Z   = (const int*)d_in[1];
    float*       out = (float*)d_out;
    const int nsite  = in_sizes[1];   // B*N = 2048

    Params prm;

    // ---- W_ORTHO = S^(-1/2) via cyclic Jacobi (double precision, host) ----
    double A[8][8], V[8][8];
    for (int i = 0; i < 8; ++i)
        for (int j = 0; j < 8; ++j) {
            const double ai = i + 1.0, aj = j + 1.0;
            A[i][j] = sqrt((5.0 + 2.0 * ai) * (5.0 + 2.0 * aj)) / (5.0 + ai + aj);
            V[i][j] = (i == j) ? 1.0 : 0.0;
        }
    for (int sweep = 0; sweep < 30; ++sweep) {
        for (int p = 0; p < 8; ++p)
            for (int q = p + 1; q < 8; ++q) {
                const double apq = A[p][q];
                if (fabs(apq) < 1e-300) continue;
                const double phi = 0.5 * atan2(2.0 * apq, A[q][q] - A[p][p]);
                const double c = cos(phi), s = sin(phi);
                for (int k = 0; k < 8; ++k) {
                    const double akp = A[k][p], akq = A[k][q];
                    A[k][p] = c * akp - s * akq;
                    A[k][q] = s * akp + c * akq;
                }
                for (int k = 0; k < 8; ++k) {
                    const double apk = A[p][k], aqk = A[q][k];
                    A[p][k] = c * apk - s * aqk;
                    A[q][k] = s * apk + c * aqk;
                }
                for (int k = 0; k < 8; ++k) {
                    const double vkp = V[k][p], vkq = V[k][q];
                    V[k][p] = c * vkp - s * vkq;
                    V[k][q] = s * vkp + c * vkq;
                }
            }
    }
    for (int i = 0; i < 8; ++i)
        for (int j = 0; j < 8; ++j) {
            double acc = 0.0;
            for (int k = 0; k < 8; ++k) acc += V[i][k] * V[j][k] / sqrt(A[k][k]);
            prm.W[i * 8 + j] = (float)acc;
        }

    for (int a = 0; a < 8; ++a)
        prm.invnorm[a] = (float)(1.0 / sqrt(pow(5.0, 2.0 * a + 7.0) / (2.0 * a + 7.0)));

    const double pi = 3.14159265358979323846;
    const double fp = 4.0 * pi;
    double yc[NM];
    yc[0]  = 0.5 * sqrt(1.0 / pi);
    yc[1]  = yc[2] = yc[3] = sqrt(3.0 / (4.0 * pi));
    yc[4]  = yc[5] = yc[7] = 0.5 * sqrt(15.0 / pi);
    yc[6]  = 0.25 * sqrt(5.0 / pi);
    yc[8]  = 0.25 * sqrt(15.0 / pi);
    yc[9]  = yc[15] = 0.25 * sqrt(35.0 / (2.0 * pi));
    yc[10] = 0.5 * sqrt(105.0 / pi);
    yc[11] = yc[13] = 0.25 * sqrt(21.0 / (2.0 * pi));
    yc[12] = 0.25 * sqrt(7.0 / pi);
    yc[14] = 0.25 * sqrt(105.0 / pi);
    yc[16] = 0.75 * sqrt(35.0 / pi);
    yc[17] = yc[23] = 0.75 * sqrt(35.0 / (2.0 * pi));
    yc[18] = 0.75 * sqrt(5.0 / pi);
    yc[19] = yc[21] = 0.75 * sqrt(5.0 / (2.0 * pi));
    yc[20] = 3.0 / 16.0 * sqrt(1.0 / pi);
    yc[22] = 3.0 / 8.0 * sqrt(5.0 / pi);
    yc[24] = 3.0 / 16.0 * sqrt(35.0 / pi);
    for (int m = 0; m < NM; ++m) prm.ycoef[m] = (float)(yc[m] * fp);

    for (int l = 0; l <= 4; ++l) prm.lscale[l] = (float)(pi * sqrt(8.0 / (2.0 * l + 1.0)));
    const float rt2 = 1.41421356237309515f;
    prm.pairf[0] = 1.f; prm.pairf[1] = rt2; prm.pairf[2] = rt2;
    prm.pairf[3] = 1.f; prm.pairf[4] = rt2; prm.pairf[5] = 1.f;

    soap_kernel<<<nsite, 256, 0, stream>>>(pos, Z, out, prm);
}

// Round 5
// 17.320 us; speedup vs baseline: 1.5010x; 1.5010x over previous
//
#include <hip/hip_runtime.h>
#include <cmath>

#define NMAX   8
#define NM     25
#define NATOM  512
#define SLOTW  33      // gy row: [0..7]=g(n), [8..32]=Y(m)
#define NOUT   1080
#define CROW   60      // per (s,n): 5 l-blocks x 12 (zero-padded)
#define CSN    480     // 8 * 60
#define CSITE  1440    // 3 * 480

struct Params {
    float W[NMAX * NMAX];   // W_ORTHO (symmetric)
    float invnorm[NMAX];
    float ycoef[NM];        // sph-harm coefficients * 4*pi
    float lscale[5];
    float pairf[6];
};

// heavy per-neighbor compute: writes g[8], Y[25] into gys row `col`
__device__ __forceinline__ void neighbor_compute(
    const float* __restrict__ pos, const Params& prm,
    float xi, float yi, float zi, int ja, int col, float* __restrict__ gys) {
    const float dx = xi - pos[ja * 3 + 0];
    const float dy = yi - pos[ja * 3 + 1];
    const float dz = zi - pos[ja * 3 + 2];
    const float d2 = dx * dx + dy * dy + dz * dz;
    const float dist = sqrtf(d2);
    const float inv  = dist > 0.f ? 1.f / dist : 0.f;
    const float x = dx * inv, y = dy * inv, z = dz * inv;
    const float x2 = x * x, y2 = y * y, z2 = z * z;
    const float r2 = x2 + y2 + z2;
    float* row = &gys[col * SLOTW];

    const float dr = 5.f - dist;
    float bas[NMAX];
    float drp = dr * dr * dr;
#pragma unroll
    for (int a = 0; a < NMAX; ++a) { bas[a] = drp * prm.invnorm[a]; drp *= dr; }
#pragma unroll
    for (int n = 0; n < NMAX; ++n) {
        float acc = 0.f;
#pragma unroll
        for (int a = 0; a < NMAX; ++a) acc += bas[a] * prm.W[n * NMAX + a];
        row[n] = acc;
    }

    row[8]  = prm.ycoef[0];
    row[9]  = prm.ycoef[1]  * y;
    row[10] = prm.ycoef[2]  * z;
    row[11] = prm.ycoef[3]  * x;
    row[12] = prm.ycoef[4]  * x * y;
    row[13] = prm.ycoef[5]  * y * z;
    row[14] = prm.ycoef[6]  * (3.f * z2 - r2);
    row[15] = prm.ycoef[7]  * x * z;
    row[16] = prm.ycoef[8]  * (x2 - y2);
    row[17] = prm.ycoef[9]  * y * (3.f * x2 - y2);
    row[18] = prm.ycoef[10] * x * y * z;
    row[19] = prm.ycoef[11] * y * (5.f * z2 - r2);
    row[20] = prm.ycoef[12] * z * (5.f * z2 - 3.f * r2);
    row[21] = prm.ycoef[13] * x * (5.f * z2 - r2);
    row[22] = prm.ycoef[14] * z * (x2 - y2);
    row[23] = prm.ycoef[15] * x * (x2 - 3.f * y2);
    row[24] = prm.ycoef[16] * x * y * (x2 - y2);
    row[25] = prm.ycoef[17] * y * z * (3.f * x2 - y2);
    row[26] = prm.ycoef[18] * x * y * (7.f * z2 - r2);
    row[27] = prm.ycoef[19] * y * z * (7.f * z2 - 3.f * r2);
    row[28] = prm.ycoef[20] * (35.f * z2 * z2 - 30.f * z2 * r2 + 3.f * r2 * r2);
    row[29] = prm.ycoef[21] * x * z * (7.f * z2 - 3.f * r2);
    row[30] = prm.ycoef[22] * (x2 - y2) * (7.f * z2 - r2);
    row[31] = prm.ycoef[23] * x * z * (x2 - 3.f * y2);
    row[32] = prm.ycoef[24] * (x2 * x2 - 6.f * x2 * y2 + y2 * y2);
}

__global__ __launch_bounds__(256)
void soap_kernel(const float* __restrict__ pos, const int* __restrict__ Z,
                 float* __restrict__ out, Params prm) {
    // one wave per site, 4 sites per block, NO __syncthreads anywhere
    __shared__ float gy_all[4][64 * SLOTW];
    __shared__ float c_all[4][CSITE];
    __shared__ int   ci_all[4][64];
    __shared__ int   sp_all[4][64];

    const int tid  = threadIdx.x;
    const int lane = tid & 63;
    const int ws   = tid >> 6;
    const int site = (blockIdx.x << 2) + ws;
    const int b    = site >> 9;
    const int jbase = b << 9;

    float* gys = gy_all[ws];
    float* cs  = c_all[ws];
    int*   cix = ci_all[ws];
    int*   sps = sp_all[ws];

    const float xi = pos[site * 3 + 0];
    const float yi = pos[site * 3 + 1];
    const float zi = pos[site * 3 + 2];

    // zero c arena (padding must read as 0)
#pragma unroll
    for (int i = 0; i < 23; ++i) {
        const int idx = lane + i * 64;
        if (idx < CSITE) cs[idx] = 0.f;
    }

    // ---- A1: cutoff scan + in-wave ballot compaction (guarded at 64) ----
    const unsigned long long ltm = (1ull << lane) - 1ull;
    int mtot = 0;
#pragma unroll
    for (int it = 0; it < 8; ++it) {
        const int ja = jbase + it * 64 + lane;
        const float dx = xi - pos[ja * 3 + 0];
        const float dy = yi - pos[ja * 3 + 1];
        const float dz = zi - pos[ja * 3 + 2];
        const float d2 = dx * dx + dy * dy + dz * dz;
        const bool pr = d2 < 25.0f;
        const unsigned long long mk = __ballot(pr);
        const int sl = mtot + __popcll(mk & ltm);
        if (pr && sl < 64) cix[sl] = ja;
        mtot += __popcll(mk);
    }
    const int M = mtot;

    const int n_own = lane & 7;
    const int mrow  = lane >> 3;
    float acc0[4] = {0.f, 0.f, 0.f, 0.f};   // species 0, m = mrow + 8k
    float acc1[4] = {0.f, 0.f, 0.f, 0.f};
    float acc2[4] = {0.f, 0.f, 0.f, 0.f};

    if (M <= 64) {
        // ---- in-wave species bucketing (deterministic) ----
        int myj = -1, sp = -1;
        if (lane < M) {
            myj = cix[lane];
            const int zz = Z[myj];
            sp = (zz == 1) ? 0 : (zz == 6) ? 1 : 2;
        }
        const unsigned long long b0 = __ballot(sp == 0);
        const unsigned long long b1 = __ballot(sp == 1);
        const unsigned long long b2 = __ballot(sp == 2);
        const int R1 = __popcll(b0);
        const int R2 = R1 + __popcll(b1);
        int np = -1;
        if (sp == 0)      np = __popcll(b0 & ltm);
        else if (sp == 1) np = R1 + __popcll(b1 & ltm);
        else if (sp == 2) np = R2 + __popcll(b2 & ltm);
        if (np >= 0) cix[np] = myj;          // reads (myj) precede writes in program order

        // ---- A2: heavy compute, lane == slot ----
        if (lane < M) neighbor_compute(pos, prm, xi, yi, zi, cix[lane], lane, gys);

        // ---- B: three contiguous species ranges ----
        for (int sl = 0; sl < R1; ++sl) {
            const float g = gys[sl * SLOTW + n_own];
#pragma unroll
            for (int k = 0; k < 4; ++k) {
                const int m = mrow + 8 * k;
                if (k < 3 || mrow == 0) acc0[k] += g * gys[sl * SLOTW + 8 + m];
            }
        }
        for (int sl = R1; sl < R2; ++sl) {
            const float g = gys[sl * SLOTW + n_own];
#pragma unroll
            for (int k = 0; k < 4; ++k) {
                const int m = mrow + 8 * k;
                if (k < 3 || mrow == 0) acc1[k] += g * gys[sl * SLOTW + 8 + m];
            }
        }
        for (int sl = R2; sl < M; ++sl) {
            const float g = gys[sl * SLOTW + n_own];
#pragma unroll
            for (int k = 0; k < 4; ++k) {
                const int m = mrow + 8 * k;
                if (k < 3 || mrow == 0) acc2[k] += g * gys[sl * SLOTW + 8 + m];
            }
        }
    } else {
        // ---- fallback (M > 64, practically unreachable): per-chunk slabs ----
        for (int it = 0; it < 8; ++it) {
            const int ja = jbase + it * 64 + lane;
            const float dx = xi - pos[ja * 3 + 0];
            const float dy = yi - pos[ja * 3 + 1];
            const float dz = zi - pos[ja * 3 + 2];
            const float d2 = dx * dx + dy * dy + dz * dz;
            const bool pr = d2 < 25.0f;
            const unsigned long long mk = __ballot(pr);
            const int cnt = __popcll(mk);
            if (pr) {
                const int sl = __popcll(mk & ltm);
                cix[sl] = ja;
                const int zz = Z[ja];
                sps[sl] = (zz == 1) ? 0 : (zz == 6) ? 1 : 2;
            }
            if (lane < cnt) neighbor_compute(pos, prm, xi, yi, zi, cix[lane], lane, gys);
            for (int sl = 0; sl < cnt; ++sl) {
                const int ss = sps[sl];          // wave-uniform
                const float g = gys[sl * SLOTW + n_own];
                float* accp = (ss == 0) ? acc0 : (ss == 1) ? acc1 : acc2;
#pragma unroll
                for (int k = 0; k < 4; ++k) {
                    const int m = mrow + 8 * k;
                    if (k < 3 || mrow == 0) accp[k] += g * gys[sl * SLOTW + 8 + m];
                }
            }
        }
    }

    // ---- write c into l-blocked padded layout ----
#pragma unroll
    for (int k = 0; k < 4; ++k) {
        const int m = mrow + 8 * k;
        if (k < 3 || mrow == 0) {
            const int l  = (int)sqrtf((float)m);   // exact at squares
            const int kk = m - l * l;
            const int base = n_own * CROW + l * 12 + kk;
            cs[0 * CSN + base] = acc0[k];
            cs[1 * CSN + base] = acc1[k];
            cs[2 * CSN + base] = acc2[k];
        }
    }

    // ---- C: 1080 outputs, uniform padded-12 float4 dot, coalesced stores ----
#pragma unroll
    for (int k = 0; k < 17; ++k) {
        const int o = k * 64 + lane;
        if (o < NOUT) {
            const int q   = o / 180;
            const int rem = o - q * 180;
            const int l   = rem / 36;
            const int t   = rem - l * 36;
            const int n = (int)((17.0f - sqrtf((float)(289 - 8 * t))) * 0.5f);
            const int p = t - ((n * (17 - n)) >> 1) + n;
            const int s1 = (q < 3) ? 0 : ((q < 5) ? 1 : 2);
            const int s2 = (q < 3) ? q : ((q < 5) ? (q - 2) : 2);
            const float4* ra = (const float4*)&cs[s1 * CSN + n * CROW + l * 12];
            const float4* rb = (const float4*)&cs[s2 * CSN + p * CROW + l * 12];
            const float4 a0 = ra[0], bb0 = rb[0];
            const float4 a1 = ra[1], bb1 = rb[1];
            const float4 a2 = ra[2], bb2 = rb[2];
            float sum = a0.x * bb0.x + a0.y * bb0.y + a0.z * bb0.z + a0.w * bb0.w
                      + a1.x * bb1.x + a1.y * bb1.y + a1.z * bb1.z + a1.w * bb1.w
                      + a2.x * bb2.x + a2.y * bb2.y + a2.z * bb2.z + a2.w * bb2.w;
            float sc = prm.pairf[q] * prm.lscale[l];
            if (n != p) sc *= 1.41421356237309515f;
            out[site * NOUT + o] = sum * sc;
        }
    }
}

extern "C" void kernel_launch(void* const* d_in, const int* in_sizes, int n_in,
                              void* d_out, int out_size, void* d_ws, size_t ws_size,
                              hipStream_t stream) {
    const float* pos = (const float*)d_in[0];
    const int*   Z   = (const int*)d_in[1];
    float*       out = (float*)d_out;
    const int nsite  = in_sizes[1];   // B*N = 2048

    Params prm;

    // ---- W_ORTHO = S^(-1/2) via cyclic Jacobi (double precision, host) ----
    double A[8][8], V[8][8];
    for (int i = 0; i < 8; ++i)
        for (int j = 0; j < 8; ++j) {
            const double ai = i + 1.0, aj = j + 1.0;
            A[i][j] = sqrt((5.0 + 2.0 * ai) * (5.0 + 2.0 * aj)) / (5.0 + ai + aj);
            V[i][j] = (i == j) ? 1.0 : 0.0;
        }
    for (int sweep = 0; sweep < 30; ++sweep) {
        for (int p = 0; p < 8; ++p)
            for (int q = p + 1; q < 8; ++q) {
                const double apq = A[p][q];
                if (fabs(apq) < 1e-300) continue;
                const double phi = 0.5 * atan2(2.0 * apq, A[q][q] - A[p][p]);
                const double c = cos(phi), s = sin(phi);
                for (int k = 0; k < 8; ++k) {
                    const double akp = A[k][p], akq = A[k][q];
                    A[k][p] = c * akp - s * akq;
                    A[k][q] = s * akp + c * akq;
                }
                for (int k = 0; k < 8; ++k) {
                    const double apk = A[p][k], aqk = A[q][k];
                    A[p][k] = c * apk - s * aqk;
                    A[q][k] = s * apk + c * aqk;
                }
                for (int k = 0; k < 8; ++k) {
                    const double vkp = V[k][p], vkq = V[k][q];
                    V[k][p] = c * vkp - s * vkq;
                    V[k][q] = s * vkp + c * vkq;
                }
            }
    }
    for (int i = 0; i < 8; ++i)
        for (int j = 0; j < 8; ++j) {
            double acc = 0.0;
            for (int k = 0; k < 8; ++k) acc += V[i][k] * V[j][k] / sqrt(A[k][k]);
            prm.W[i * 8 + j] = (float)acc;
        }

    for (int a = 0; a < 8; ++a)
        prm.invnorm[a] = (float)(1.0 / sqrt(pow(5.0, 2.0 * a + 7.0) / (2.0 * a + 7.0)));

    const double pi = 3.14159265358979323846;
    const double fp = 4.0 * pi;
    double yc[NM];
    yc[0]  = 0.5 * sqrt(1.0 / pi);
    yc[1]  = yc[2] = yc[3] = sqrt(3.0 / (4.0 * pi));
    yc[4]  = yc[5] = yc[7] = 0.5 * sqrt(15.0 / pi);
    yc[6]  = 0.25 * sqrt(5.0 / pi);
    yc[8]  = 0.25 * sqrt(15.0 / pi);
    yc[9]  = yc[15] = 0.25 * sqrt(35.0 / (2.0 * pi));
    yc[10] = 0.5 * sqrt(105.0 / pi);
    yc[11] = yc[13] = 0.25 * sqrt(21.0 / (2.0 * pi));
    yc[12] = 0.25 * sqrt(7.0 / pi);
    yc[14] = 0.25 * sqrt(105.0 / pi);
    yc[16] = 0.75 * sqrt(35.0 / pi);
    yc[17] = yc[23] = 0.75 * sqrt(35.0 / (2.0 * pi));
    yc[18] = 0.75 * sqrt(5.0 / pi);
    yc[19] = yc[21] = 0.75 * sqrt(5.0 / (2.0 * pi));
    yc[20] = 3.0 / 16.0 * sqrt(1.0 / pi);
    yc[22] = 3.0 / 8.0 * sqrt(5.0 / pi);
    yc[24] = 3.0 / 16.0 * sqrt(35.0 / pi);
    for (int m = 0; m < NM; ++m) prm.ycoef[m] = (float)(yc[m] * fp);

    for (int l = 0; l <= 4; ++l) prm.lscale[l] = (float)(pi * sqrt(8.0 / (2.0 * l + 1.0)));
    const float rt2 = 1.41421356237309515f;
    prm.pairf[0] = 1.f; prm.pairf[1] = rt2; prm.pairf[2] = rt2;
    prm.pairf[3] = 1.f; prm.pairf[4] = rt2; prm.pairf[5] = 1.f;

    soap_kernel<<<(nsite + 3) / 4, 256, 0, stream>>>(pos, Z, out, prm);
}